// Round 2
// baseline (319.030 us; speedup 1.0000x reference)
//
#include <hip/hip_runtime.h>

#define BT_D  512
#define BT_D4 128   // D / 4 float4 groups per row

// Kernel 1: per-column partial sums (Se, Se2, St, St2, Set), accumulated
// via atomics into nslot copies of a 5*512-float accumulator in d_ws.
__global__ __launch_bounds__(256) void bt_partial_kernel(
    const float4* __restrict__ e4, const float4* __restrict__ t4,
    float* __restrict__ acc, int B, int nblk, int nslot)
{
    const int tid = threadIdx.x;
    const int c4  = tid & (BT_D4 - 1);   // which float4 column group
    const int r   = tid >> 7;            // row parity within block (0/1)

    float4 se  = make_float4(0.f, 0.f, 0.f, 0.f);
    float4 se2 = make_float4(0.f, 0.f, 0.f, 0.f);
    float4 st  = make_float4(0.f, 0.f, 0.f, 0.f);
    float4 st2 = make_float4(0.f, 0.f, 0.f, 0.f);
    float4 set = make_float4(0.f, 0.f, 0.f, 0.f);

    const int stride = nblk * 2;
    for (int row = blockIdx.x * 2 + r; row < B; row += stride) {
        const size_t idx = (size_t)row * BT_D4 + c4;
        const float4 ev = e4[idx];
        const float4 tv = t4[idx];
        se.x += ev.x; se.y += ev.y; se.z += ev.z; se.w += ev.w;
        st.x += tv.x; st.y += tv.y; st.z += tv.z; st.w += tv.w;
        se2.x = fmaf(ev.x, ev.x, se2.x);
        se2.y = fmaf(ev.y, ev.y, se2.y);
        se2.z = fmaf(ev.z, ev.z, se2.z);
        se2.w = fmaf(ev.w, ev.w, se2.w);
        st2.x = fmaf(tv.x, tv.x, st2.x);
        st2.y = fmaf(tv.y, tv.y, st2.y);
        st2.z = fmaf(tv.z, tv.z, st2.z);
        st2.w = fmaf(tv.w, tv.w, st2.w);
        set.x = fmaf(ev.x, tv.x, set.x);
        set.y = fmaf(ev.y, tv.y, set.y);
        set.z = fmaf(ev.z, tv.z, set.z);
        set.w = fmaf(ev.w, tv.w, set.w);
    }

    // fold r==1 half-block into r==0 via LDS
    __shared__ float4 lds[BT_D4][5];
    if (r == 1) {
        lds[c4][0] = se;  lds[c4][1] = se2; lds[c4][2] = st;
        lds[c4][3] = st2; lds[c4][4] = set;
    }
    __syncthreads();
    if (r == 0) {
        float4 a;
        a = lds[c4][0]; se.x += a.x; se.y += a.y; se.z += a.z; se.w += a.w;
        a = lds[c4][1]; se2.x += a.x; se2.y += a.y; se2.z += a.z; se2.w += a.w;
        a = lds[c4][2]; st.x += a.x; st.y += a.y; st.z += a.z; st.w += a.w;
        a = lds[c4][3]; st2.x += a.x; st2.y += a.y; st2.z += a.z; st2.w += a.w;
        a = lds[c4][4]; set.x += a.x; set.y += a.y; set.z += a.z; set.w += a.w;

        float* ap = acc + (size_t)(blockIdx.x % nslot) * (5 * BT_D);
        const int col = c4 * 4;
        atomicAdd(&ap[0 * BT_D + col + 0], se.x);
        atomicAdd(&ap[0 * BT_D + col + 1], se.y);
        atomicAdd(&ap[0 * BT_D + col + 2], se.z);
        atomicAdd(&ap[0 * BT_D + col + 3], se.w);
        atomicAdd(&ap[1 * BT_D + col + 0], se2.x);
        atomicAdd(&ap[1 * BT_D + col + 1], se2.y);
        atomicAdd(&ap[1 * BT_D + col + 2], se2.z);
        atomicAdd(&ap[1 * BT_D + col + 3], se2.w);
        atomicAdd(&ap[2 * BT_D + col + 0], st.x);
        atomicAdd(&ap[2 * BT_D + col + 1], st.y);
        atomicAdd(&ap[2 * BT_D + col + 2], st.z);
        atomicAdd(&ap[2 * BT_D + col + 3], st.w);
        atomicAdd(&ap[3 * BT_D + col + 0], st2.x);
        atomicAdd(&ap[3 * BT_D + col + 1], st2.y);
        atomicAdd(&ap[3 * BT_D + col + 2], st2.z);
        atomicAdd(&ap[3 * BT_D + col + 3], st2.w);
        atomicAdd(&ap[4 * BT_D + col + 0], set.x);
        atomicAdd(&ap[4 * BT_D + col + 1], set.y);
        atomicAdd(&ap[4 * BT_D + col + 2], set.z);
        atomicAdd(&ap[4 * BT_D + col + 3], set.w);
    }
}

// Kernel 2: finalize per-column stats (fp64 for safety) + block reduce.
__global__ __launch_bounds__(512) void bt_final_kernel(
    const float* __restrict__ acc, float* __restrict__ out, int B, int nslot)
{
    const int d = threadIdx.x;   // one thread per column, 512 threads
    double Se = 0, Se2 = 0, St = 0, St2 = 0, Set = 0;
    for (int s = 0; s < nslot; ++s) {
        const float* a = acc + (size_t)s * (5 * BT_D);
        Se  += a[0 * BT_D + d];
        Se2 += a[1 * BT_D + d];
        St  += a[2 * BT_D + d];
        St2 += a[3 * BT_D + d];
        Set += a[4 * BT_D + d];
    }
    const double Bd = (double)B;
    const double me = Se / Bd, mt = St / Bd;
    double ve = (Se2 - Bd * me * me) / (Bd - 1.0);
    double vt = (St2 - Bd * mt * mt) / (Bd - 1.0);
    ve = ve > 0.0 ? ve : 0.0;
    vt = vt > 0.0 ? vt : 0.0;
    const double sd_e = sqrt(ve) + 1e-9;
    const double sd_t = sqrt(vt) + 1e-9;
    const double c = (Set - Bd * me * mt) / (sd_e * sd_t * Bd);
    const double v = (1.0 - c) * (1.0 - c);

    __shared__ double red[BT_D];
    red[d] = v;
    __syncthreads();
    for (int s = BT_D / 2; s > 0; s >>= 1) {
        if (d < s) red[d] += red[d + s];
        __syncthreads();
    }
    if (d == 0) out[0] = (float)red[0];
}

extern "C" void kernel_launch(void* const* d_in, const int* in_sizes, int n_in,
                              void* d_out, int out_size, void* d_ws, size_t ws_size,
                              hipStream_t stream) {
    const float* e   = (const float*)d_in[0];
    const float* tau = (const float*)d_in[1];
    const int B = in_sizes[0] / BT_D;
    float* acc = (float*)d_ws;

    // pick #accumulator copies that fits the workspace (contention control)
    int nslot = 1;
    const size_t slot_bytes = (size_t)5 * BT_D * sizeof(float);
    if (ws_size >= 8 * slot_bytes)      nslot = 8;
    else if (ws_size >= 4 * slot_bytes) nslot = 4;
    else if (ws_size >= 2 * slot_bytes) nslot = 2;

    (void)hipMemsetAsync(d_ws, 0, (size_t)nslot * slot_bytes, stream);

    const int nblk = 1024;
    bt_partial_kernel<<<nblk, 256, 0, stream>>>(
        (const float4*)e, (const float4*)tau, acc, B, nblk, nslot);
    bt_final_kernel<<<1, BT_D, 0, stream>>>(acc, (float*)d_out, B, nslot);
}

// Round 3
// 315.943 us; speedup vs baseline: 1.0098x; 1.0098x over previous
//
#include <hip/hip_runtime.h>

#define BT_D  512
#define BT_D4 128   // D / 4 float4 groups per row
#define NBLK  2048  // 8 blocks/CU on 256 CUs
#define NTHR  256

// Accumulate one (e,tau) float4 pair into the 5 stat accumulators.
#define BT_ACC(ev, tv)                                                  \
    do {                                                                \
        se.x += (ev).x; se.y += (ev).y; se.z += (ev).z; se.w += (ev).w; \
        st.x += (tv).x; st.y += (tv).y; st.z += (tv).z; st.w += (tv).w; \
        se2.x = fmaf((ev).x, (ev).x, se2.x);                            \
        se2.y = fmaf((ev).y, (ev).y, se2.y);                            \
        se2.z = fmaf((ev).z, (ev).z, se2.z);                            \
        se2.w = fmaf((ev).w, (ev).w, se2.w);                            \
        st2.x = fmaf((tv).x, (tv).x, st2.x);                            \
        st2.y = fmaf((tv).y, (tv).y, st2.y);                            \
        st2.z = fmaf((tv).z, (tv).z, st2.z);                            \
        st2.w = fmaf((tv).w, (tv).w, st2.w);                            \
        set.x = fmaf((ev).x, (tv).x, set.x);                            \
        set.y = fmaf((ev).y, (tv).y, set.y);                            \
        set.z = fmaf((ev).z, (tv).z, set.z);                            \
        set.w = fmaf((ev).w, (tv).w, set.w);                            \
    } while (0)

// Kernel 1: flat grid-stride over the N4 = B*128 float4 stream. Total thread
// count is a multiple of 128, so each thread always owns column group
// c4 = tid & 127. Unroll-by-4 with all 8 loads issued before any consume
// (memory-level parallelism) — this is the whole point vs R2.
__global__ __launch_bounds__(NTHR) void bt_partial_kernel(
    const float4* __restrict__ e4, const float4* __restrict__ t4,
    float* __restrict__ acc, int B, int nslot)
{
    const int tid = threadIdx.x;
    const int c4  = tid & (BT_D4 - 1);
    const int r   = tid >> 7;

    float4 se  = make_float4(0.f, 0.f, 0.f, 0.f);
    float4 se2 = make_float4(0.f, 0.f, 0.f, 0.f);
    float4 st  = make_float4(0.f, 0.f, 0.f, 0.f);
    float4 st2 = make_float4(0.f, 0.f, 0.f, 0.f);
    float4 set = make_float4(0.f, 0.f, 0.f, 0.f);

    const size_t T  = (size_t)gridDim.x * NTHR;
    const size_t N4 = (size_t)B * BT_D4;
    size_t i = (size_t)blockIdx.x * NTHR + tid;

    for (; i + 3 * T < N4; i += 4 * T) {
        const float4 e0 = e4[i];
        const float4 e1 = e4[i + T];
        const float4 e2 = e4[i + 2 * T];
        const float4 e3 = e4[i + 3 * T];
        const float4 t0 = t4[i];
        const float4 t1 = t4[i + T];
        const float4 t2 = t4[i + 2 * T];
        const float4 t3 = t4[i + 3 * T];
        BT_ACC(e0, t0);
        BT_ACC(e1, t1);
        BT_ACC(e2, t2);
        BT_ACC(e3, t3);
    }
    for (; i < N4; i += T) {
        const float4 ev = e4[i];
        const float4 tv = t4[i];
        BT_ACC(ev, tv);
    }

    // fold r==1 half-block into r==0 via LDS
    __shared__ float4 lds[BT_D4][5];
    if (r == 1) {
        lds[c4][0] = se;  lds[c4][1] = se2; lds[c4][2] = st;
        lds[c4][3] = st2; lds[c4][4] = set;
    }
    __syncthreads();
    if (r == 0) {
        float4 a;
        a = lds[c4][0]; se.x += a.x; se.y += a.y; se.z += a.z; se.w += a.w;
        a = lds[c4][1]; se2.x += a.x; se2.y += a.y; se2.z += a.z; se2.w += a.w;
        a = lds[c4][2]; st.x += a.x; st.y += a.y; st.z += a.z; st.w += a.w;
        a = lds[c4][3]; st2.x += a.x; st2.y += a.y; st2.z += a.z; st2.w += a.w;
        a = lds[c4][4]; set.x += a.x; set.y += a.y; set.z += a.z; set.w += a.w;

        float* ap = acc + (size_t)(blockIdx.x % nslot) * (5 * BT_D);
        const int col = c4 * 4;
        atomicAdd(&ap[0 * BT_D + col + 0], se.x);
        atomicAdd(&ap[0 * BT_D + col + 1], se.y);
        atomicAdd(&ap[0 * BT_D + col + 2], se.z);
        atomicAdd(&ap[0 * BT_D + col + 3], se.w);
        atomicAdd(&ap[1 * BT_D + col + 0], se2.x);
        atomicAdd(&ap[1 * BT_D + col + 1], se2.y);
        atomicAdd(&ap[1 * BT_D + col + 2], se2.z);
        atomicAdd(&ap[1 * BT_D + col + 3], se2.w);
        atomicAdd(&ap[2 * BT_D + col + 0], st.x);
        atomicAdd(&ap[2 * BT_D + col + 1], st.y);
        atomicAdd(&ap[2 * BT_D + col + 2], st.z);
        atomicAdd(&ap[2 * BT_D + col + 3], st.w);
        atomicAdd(&ap[3 * BT_D + col + 0], st2.x);
        atomicAdd(&ap[3 * BT_D + col + 1], st2.y);
        atomicAdd(&ap[3 * BT_D + col + 2], st2.z);
        atomicAdd(&ap[3 * BT_D + col + 3], st2.w);
        atomicAdd(&ap[4 * BT_D + col + 0], set.x);
        atomicAdd(&ap[4 * BT_D + col + 1], set.y);
        atomicAdd(&ap[4 * BT_D + col + 2], set.z);
        atomicAdd(&ap[4 * BT_D + col + 3], set.w);
    }
}

// Kernel 2: finalize per-column stats (fp64 for safety) + block reduce.
__global__ __launch_bounds__(512) void bt_final_kernel(
    const float* __restrict__ acc, float* __restrict__ out, int B, int nslot)
{
    const int d = threadIdx.x;   // one thread per column, 512 threads
    double Se = 0, Se2 = 0, St = 0, St2 = 0, Set = 0;
    for (int s = 0; s < nslot; ++s) {
        const float* a = acc + (size_t)s * (5 * BT_D);
        Se  += a[0 * BT_D + d];
        Se2 += a[1 * BT_D + d];
        St  += a[2 * BT_D + d];
        St2 += a[3 * BT_D + d];
        Set += a[4 * BT_D + d];
    }
    const double Bd = (double)B;
    const double me = Se / Bd, mt = St / Bd;
    double ve = (Se2 - Bd * me * me) / (Bd - 1.0);
    double vt = (St2 - Bd * mt * mt) / (Bd - 1.0);
    ve = ve > 0.0 ? ve : 0.0;
    vt = vt > 0.0 ? vt : 0.0;
    const double sd_e = sqrt(ve) + 1e-9;
    const double sd_t = sqrt(vt) + 1e-9;
    const double c = (Set - Bd * me * mt) / (sd_e * sd_t * Bd);
    const double v = (1.0 - c) * (1.0 - c);

    __shared__ double red[BT_D];
    red[d] = v;
    __syncthreads();
    for (int s = BT_D / 2; s > 0; s >>= 1) {
        if (d < s) red[d] += red[d + s];
        __syncthreads();
    }
    if (d == 0) out[0] = (float)red[0];
}

extern "C" void kernel_launch(void* const* d_in, const int* in_sizes, int n_in,
                              void* d_out, int out_size, void* d_ws, size_t ws_size,
                              hipStream_t stream) {
    const float* e   = (const float*)d_in[0];
    const float* tau = (const float*)d_in[1];
    const int B = in_sizes[0] / BT_D;
    float* acc = (float*)d_ws;

    // pick #accumulator copies that fits the workspace (atomic-chain depth
    // control: 2048 blocks / nslot same-address adds per element)
    int nslot = 1;
    const size_t slot_bytes = (size_t)5 * BT_D * sizeof(float);
    if (ws_size >= 32 * slot_bytes)      nslot = 32;
    else if (ws_size >= 8 * slot_bytes)  nslot = 8;
    else if (ws_size >= 4 * slot_bytes)  nslot = 4;
    else if (ws_size >= 2 * slot_bytes)  nslot = 2;

    (void)hipMemsetAsync(d_ws, 0, (size_t)nslot * slot_bytes, stream);

    bt_partial_kernel<<<NBLK, NTHR, 0, stream>>>(
        (const float4*)e, (const float4*)tau, acc, B, nslot);
    bt_final_kernel<<<1, BT_D, 0, stream>>>(acc, (float*)d_out, B, nslot);
}

// Round 4
// 290.256 us; speedup vs baseline: 1.0991x; 1.0885x over previous
//
#include <hip/hip_runtime.h>

#define BT_D  512
#define BT_D4 128   // D / 4 float4 groups per row
#define NBLK  1024  // 4 blocks/CU on 256 CUs — all co-resident at 4 waves/EU
#define NTHR  256
#define BT_U  8     // unroll depth: 16 independent 16B loads in flight/wave

// Accumulate one (e,tau) float4 pair into the 5 stat accumulators.
#define BT_ACC(ev, tv)                                                  \
    do {                                                                \
        se.x += (ev).x; se.y += (ev).y; se.z += (ev).z; se.w += (ev).w; \
        st.x += (tv).x; st.y += (tv).y; st.z += (tv).z; st.w += (tv).w; \
        se2.x = fmaf((ev).x, (ev).x, se2.x);                            \
        se2.y = fmaf((ev).y, (ev).y, se2.y);                            \
        se2.z = fmaf((ev).z, (ev).z, se2.z);                            \
        se2.w = fmaf((ev).w, (ev).w, se2.w);                            \
        st2.x = fmaf((tv).x, (tv).x, st2.x);                            \
        st2.y = fmaf((tv).y, (tv).y, st2.y);                            \
        st2.z = fmaf((tv).z, (tv).z, st2.z);                            \
        st2.w = fmaf((tv).w, (tv).w, st2.w);                            \
        set.x = fmaf((ev).x, (tv).x, set.x);                            \
        set.y = fmaf((ev).y, (tv).y, set.y);                            \
        set.z = fmaf((ev).z, (tv).z, set.z);                            \
        set.w = fmaf((ev).w, (tv).w, set.w);                            \
    } while (0)

// Kernel 1: flat grid-stride over the N4 = B*128 float4 stream.
// __launch_bounds__(256,4): 4 waves/EU min → 128-VGPR budget, enough to
// keep all 16 unrolled loads live simultaneously (R3 got squeezed to 40
// VGPRs and serialized every load → 1.7 TB/s).
__global__ __launch_bounds__(NTHR, 4) void bt_partial_kernel(
    const float4* __restrict__ e4, const float4* __restrict__ t4,
    float* __restrict__ acc, int B, int nslot)
{
    const int tid = threadIdx.x;
    const int c4  = tid & (BT_D4 - 1);
    const int r   = tid >> 7;

    float4 se  = make_float4(0.f, 0.f, 0.f, 0.f);
    float4 se2 = make_float4(0.f, 0.f, 0.f, 0.f);
    float4 st  = make_float4(0.f, 0.f, 0.f, 0.f);
    float4 st2 = make_float4(0.f, 0.f, 0.f, 0.f);
    float4 set = make_float4(0.f, 0.f, 0.f, 0.f);

    const size_t T  = (size_t)gridDim.x * NTHR;
    const size_t N4 = (size_t)B * BT_D4;
    size_t i = (size_t)blockIdx.x * NTHR + tid;

    for (; i + (BT_U - 1) * T < N4; i += BT_U * T) {
        float4 ev[BT_U], tv[BT_U];
#pragma unroll
        for (int u = 0; u < BT_U; ++u) {
            ev[u] = e4[i + u * T];
            tv[u] = t4[i + u * T];
        }
#pragma unroll
        for (int u = 0; u < BT_U; ++u) BT_ACC(ev[u], tv[u]);
    }
    for (; i < N4; i += T) {
        const float4 ev = e4[i];
        const float4 tv = t4[i];
        BT_ACC(ev, tv);
    }

    // fold r==1 half-block into r==0 via LDS
    __shared__ float4 lds[BT_D4][5];
    if (r == 1) {
        lds[c4][0] = se;  lds[c4][1] = se2; lds[c4][2] = st;
        lds[c4][3] = st2; lds[c4][4] = set;
    }
    __syncthreads();
    if (r == 0) {
        float4 a;
        a = lds[c4][0]; se.x += a.x; se.y += a.y; se.z += a.z; se.w += a.w;
        a = lds[c4][1]; se2.x += a.x; se2.y += a.y; se2.z += a.z; se2.w += a.w;
        a = lds[c4][2]; st.x += a.x; st.y += a.y; st.z += a.z; st.w += a.w;
        a = lds[c4][3]; st2.x += a.x; st2.y += a.y; st2.z += a.z; st2.w += a.w;
        a = lds[c4][4]; set.x += a.x; set.y += a.y; set.z += a.z; set.w += a.w;

        float* ap = acc + (size_t)(blockIdx.x % nslot) * (5 * BT_D);
        const int col = c4 * 4;
        atomicAdd(&ap[0 * BT_D + col + 0], se.x);
        atomicAdd(&ap[0 * BT_D + col + 1], se.y);
        atomicAdd(&ap[0 * BT_D + col + 2], se.z);
        atomicAdd(&ap[0 * BT_D + col + 3], se.w);
        atomicAdd(&ap[1 * BT_D + col + 0], se2.x);
        atomicAdd(&ap[1 * BT_D + col + 1], se2.y);
        atomicAdd(&ap[1 * BT_D + col + 2], se2.z);
        atomicAdd(&ap[1 * BT_D + col + 3], se2.w);
        atomicAdd(&ap[2 * BT_D + col + 0], st.x);
        atomicAdd(&ap[2 * BT_D + col + 1], st.y);
        atomicAdd(&ap[2 * BT_D + col + 2], st.z);
        atomicAdd(&ap[2 * BT_D + col + 3], st.w);
        atomicAdd(&ap[3 * BT_D + col + 0], st2.x);
        atomicAdd(&ap[3 * BT_D + col + 1], st2.y);
        atomicAdd(&ap[3 * BT_D + col + 2], st2.z);
        atomicAdd(&ap[3 * BT_D + col + 3], st2.w);
        atomicAdd(&ap[4 * BT_D + col + 0], set.x);
        atomicAdd(&ap[4 * BT_D + col + 1], set.y);
        atomicAdd(&ap[4 * BT_D + col + 2], set.z);
        atomicAdd(&ap[4 * BT_D + col + 3], set.w);
    }
}

// Kernel 2: finalize per-column stats (fp64 for safety) + block reduce.
__global__ __launch_bounds__(512) void bt_final_kernel(
    const float* __restrict__ acc, float* __restrict__ out, int B, int nslot)
{
    const int d = threadIdx.x;   // one thread per column, 512 threads
    double Se = 0, Se2 = 0, St = 0, St2 = 0, Set = 0;
    for (int s = 0; s < nslot; ++s) {
        const float* a = acc + (size_t)s * (5 * BT_D);
        Se  += a[0 * BT_D + d];
        Se2 += a[1 * BT_D + d];
        St  += a[2 * BT_D + d];
        St2 += a[3 * BT_D + d];
        Set += a[4 * BT_D + d];
    }
    const double Bd = (double)B;
    const double me = Se / Bd, mt = St / Bd;
    double ve = (Se2 - Bd * me * me) / (Bd - 1.0);
    double vt = (St2 - Bd * mt * mt) / (Bd - 1.0);
    ve = ve > 0.0 ? ve : 0.0;
    vt = vt > 0.0 ? vt : 0.0;
    const double sd_e = sqrt(ve) + 1e-9;
    const double sd_t = sqrt(vt) + 1e-9;
    const double c = (Set - Bd * me * mt) / (sd_e * sd_t * Bd);
    const double v = (1.0 - c) * (1.0 - c);

    __shared__ double red[BT_D];
    red[d] = v;
    __syncthreads();
    for (int s = BT_D / 2; s > 0; s >>= 1) {
        if (d < s) red[d] += red[d + s];
        __syncthreads();
    }
    if (d == 0) out[0] = (float)red[0];
}

extern "C" void kernel_launch(void* const* d_in, const int* in_sizes, int n_in,
                              void* d_out, int out_size, void* d_ws, size_t ws_size,
                              hipStream_t stream) {
    const float* e   = (const float*)d_in[0];
    const float* tau = (const float*)d_in[1];
    const int B = in_sizes[0] / BT_D;
    float* acc = (float*)d_ws;

    // accumulator copies: atomic same-address chain depth = NBLK / nslot
    int nslot = 1;
    const size_t slot_bytes = (size_t)5 * BT_D * sizeof(float);
    if (ws_size >= 32 * slot_bytes)      nslot = 32;
    else if (ws_size >= 8 * slot_bytes)  nslot = 8;
    else if (ws_size >= 4 * slot_bytes)  nslot = 4;
    else if (ws_size >= 2 * slot_bytes)  nslot = 2;

    (void)hipMemsetAsync(d_ws, 0, (size_t)nslot * slot_bytes, stream);

    bt_partial_kernel<<<NBLK, NTHR, 0, stream>>>(
        (const float4*)e, (const float4*)tau, acc, B, nslot);
    bt_final_kernel<<<1, BT_D, 0, stream>>>(acc, (float*)d_out, B, nslot);
}